// Round 4
// baseline (214.495 us; speedup 1.0000x reference)
//
#include <hip/hip_runtime.h>
#include <hip/hip_fp16.h>

typedef float f32x4 __attribute__((ext_vector_type(4)));

// LeNet C3 connection table: input channel ii feeds CONN[ii][j] with weight[j][ii].
__device__ constexpr int CONN[6][10] = {
    {0, 4, 5, 6, 9, 10, 11, 12, 14, 15},
    {0, 1, 5, 6, 7, 10, 11, 12, 13, 15},
    {0, 1, 2, 6, 7, 8, 11, 13, 14, 15},
    {1, 2, 3, 6, 7, 8, 9, 12, 14, 15},
    {2, 3, 4, 7, 8, 9, 10, 12, 13, 15},
    {3, 4, 5, 8, 9, 10, 11, 13, 14, 15}};

// How many lists contain channel c (bias multiplier).
__device__ constexpr int CNT[16] = {3,3,3,3,3,3,4,4,4,4,4,4,4,4,4,6};

__device__ __forceinline__ __half2 u2h2(unsigned u) { __half2 h; __builtin_memcpy(&h, &u, 4); return h; }
__device__ __forceinline__ unsigned h22u(__half2 h) { unsigned u; __builtin_memcpy(&u, &h, 4); return u; }

// Pack weights to broadcast-half2 table: wt[ii*250 + r*50 + kx*10 + j] = (h,h)
__global__ void prep_weights(const float* __restrict__ w, unsigned* __restrict__ wt) {
    int t = blockIdx.x * 256 + threadIdx.x;
    if (t < 1500) {
        int j = t % 10, kx = (t / 10) % 5, r = (t / 50) % 5, ii = t / 250;
        __half hw = __float2half(w[j * 150 + ii * 25 + r * 5 + kx]);
        wt[t] = h22u(__halves2half2(hw, hw));
    }
}

// Tile: 32y x 32x outputs, 256 threads, PX=4 px/thread (tx 0..7, ty 0..31).
// LDS: 6ch x 36 rows x 10 8B-units (fp16), XOR-swizzled units (u<8: u^row&7).
__global__ __launch_bounds__(256, 3) void c3_kernel(
    const float* __restrict__ x, const unsigned* __restrict__ wt,
    const float* __restrict__ bias, float* __restrict__ out)
{
    __shared__ unsigned long long s64[2160];  // 17280 B
    char* s_raw = (char*)s64;

    const int tid = threadIdx.x;
    const int x0 = blockIdx.x * 32;
    const int y0 = blockIdx.y * 32;
    const int n  = blockIdx.z;
    const float* xin = x + (size_t)n * 6 * 65536;

    // ---- stage 6ch x 36row x 9 float4 tile as fp16, swizzled ----
    for (int f = tid; f < 1944; f += 256) {
        int c4  = f % 9;
        int t   = f / 9;
        int row = t % 36;
        int ch  = t / 36;
        int gr  = y0 + row; if (gr > 255) gr = 255;          // OOB rows feed only discarded outputs
        int gc4 = (x0 >> 2) + c4; if (gc4 > 63) gc4 = 63;
        float4 v = *reinterpret_cast<const float4*>(xin + (size_t)ch * 65536 + gr * 256 + gc4 * 4);
        int e  = row & 7;
        int pu = (c4 < 8) ? (c4 ^ e) : c4;                   // XOR swizzle on 8B units
        unsigned lo = h22u(__floats2half2_rn(v.x, v.y));
        unsigned hi = h22u(__floats2half2_rn(v.z, v.w));
        *reinterpret_cast<uint2*>(s_raw + ch * 2880 + row * 80 + pu * 8) = make_uint2(lo, hi);
    }
    __syncthreads();

    const int tx = tid & 7;    // 8 threads across x, 4 px each
    const int ty = tid >> 3;   // 32 rows

    float accf[4][16];
    #pragma unroll
    for (int p = 0; p < 4; ++p)
        #pragma unroll
        for (int c = 0; c < 16; ++c) accf[p][c] = 0.f;

    const __half2 z2 = __float2half2_rn(0.f);

    #pragma unroll
    for (int ii = 0; ii < 6; ++ii) {
        __half2 acch0[16], acch1[16];   // only CONN[ii] entries live (static indices)
        #pragma unroll
        for (int j = 0; j < 10; ++j) { acch0[CONN[ii][j]] = z2; acch1[CONN[ii][j]] = z2; }

        #pragma unroll 1   // code size: keep one copy of the 100-pk_fma body per ii
        for (int r = 0; r < 5; ++r) {
            const int row = ty + r;
            const int e = row & 7;
            const char* base = s_raw + ii * 2880 + row * 80;
            // window: halves 4tx..4tx+7 = 8B units tx, tx+1 (swizzled separately)
            uint2 a = *reinterpret_cast<const uint2*>(base + (tx ^ e) * 8);
            const int u1 = tx + 1;
            const int pu1 = (u1 < 8) ? (u1 ^ e) : u1;
            uint2 b = *reinterpret_cast<const uint2*>(base + pu1 * 8);
            __half2 w0 = u2h2(a.x), w1 = u2h2(a.y), w2 = u2h2(b.x), w3 = u2h2(b.y);
            // odd-parity pairs
            __half2 o0 = __halves2half2(__high2half(w0), __low2half(w1));
            __half2 o1 = __halves2half2(__high2half(w1), __low2half(w2));
            __half2 o2 = __halves2half2(__high2half(w2), __low2half(w3));

            const unsigned* wr = wt + ii * 250 + r * 50;   // wave-uniform -> s_load
            #pragma unroll
            for (int kx = 0; kx < 5; ++kx) {
                __half2 e0 = (kx == 0) ? w0 : (kx == 1) ? o0 : (kx == 2) ? w1 : (kx == 3) ? o1 : w2;
                __half2 e1 = (kx == 0) ? w1 : (kx == 1) ? o1 : (kx == 2) ? w2 : (kx == 3) ? o2 : w3;
                #pragma unroll
                for (int j = 0; j < 10; ++j) {
                    __half2 wv = u2h2(wr[kx * 10 + j]);
                    const int c = CONN[ii][j];
                    acch0[c] = __hfma2(e0, wv, acch0[c]);
                    acch1[c] = __hfma2(e1, wv, acch1[c]);
                }
            }
        }
        // widen per-ii fp16 partials into f32 master accumulators
        #pragma unroll
        for (int j = 0; j < 10; ++j) {
            const int c = CONN[ii][j];
            float2 f0 = __half22float2(acch0[c]);
            float2 f1 = __half22float2(acch1[c]);
            accf[0][c] += f0.x; accf[1][c] += f0.y;
            accf[2][c] += f1.x; accf[3][c] += f1.y;
        }
    }

    // ---- epilogue: bias*count, guarded nontemporal float4 stores ----
    const int oy = y0 + ty;
    const int ox = x0 + tx * 4;
    if (oy < 252 && ox + 3 < 252) {
        float* op = out + (size_t)n * 16 * 63504 + (size_t)oy * 252 + ox;
        #pragma unroll
        for (int c = 0; c < 16; ++c) {
            float bb = bias[c] * (float)CNT[c];
            f32x4 v = { accf[0][c] + bb, accf[1][c] + bb,
                        accf[2][c] + bb, accf[3][c] + bb };
            __builtin_nontemporal_store(v, reinterpret_cast<f32x4*>(op + (size_t)c * 63504));
        }
    }
}

extern "C" void kernel_launch(void* const* d_in, const int* in_sizes, int n_in,
                              void* d_out, int out_size, void* d_ws, size_t ws_size,
                              hipStream_t stream) {
    const float* x    = (const float*)d_in[0];  // (64,6,256,256)
    const float* w    = (const float*)d_in[1];  // (10,6,5,5)
    const float* bias = (const float*)d_in[2];  // (1,16,1,1)
    float* out = (float*)d_out;                 // (64,16,252,252)
    unsigned* wt = (unsigned*)d_ws;             // 1500 dwords of packed (h,h) weights

    hipLaunchKernelGGL(prep_weights, dim3(6), dim3(256), 0, stream, w, wt);
    dim3 grid(8, 8, 64);
    hipLaunchKernelGGL(c3_kernel, grid, dim3(256), 0, stream, x, wt, bias, out);
}